// Round 1
// baseline (321.767 us; speedup 1.0000x reference)
//
#include <hip/hip_runtime.h>
#include <stdint.h>

#define D_MODEL 1024
#define N_HEADS 16
#define D_HEAD 64
#define BATCH 4
#define SEQ 2048
#define MTOT (BATCH * SEQ)   // 8192

typedef unsigned short u16;
typedef __attribute__((ext_vector_type(8))) short bf16x8;
typedef __attribute__((ext_vector_type(4))) float f32x4;

#define MFMA(a, b, c) __builtin_amdgcn_mfma_f32_16x16x32_bf16((a), (b), (c), 0, 0, 0)
#define LOG2E 1.4426950408889634f
#define SC (0.125f * LOG2E)   // folded into Wq at cvt time

// fp32 -> bf16 bits, round-to-nearest-even
static __device__ __forceinline__ u16 f2bf(float f) {
  unsigned u = __builtin_bit_cast(unsigned, f);
  u += 0x7fffu + ((u >> 16) & 1u);
  return (u16)(u >> 16);
}
// truncating (1 inst) — for p >= 0, error < 1 ulp
static __device__ __forceinline__ u16 f2bf_t(float f) {
  return (u16)(__builtin_bit_cast(unsigned, f) >> 16);
}

// async 16B global->LDS (dest = wave-uniform base + lane*16)
static __device__ __forceinline__ void gload_lds16(const void* g, void* l) {
  __builtin_amdgcn_global_load_lds(
      (const __attribute__((address_space(1))) void*)g,
      (__attribute__((address_space(3))) void*)l, 16, 0, 0);
}

// ---- converts ----
__global__ __launch_bounds__(256) void cvt3(const float* __restrict__ a,
                                            const float* __restrict__ b,
                                            const float* __restrict__ c,
                                            u16* __restrict__ oa, u16* __restrict__ ob,
                                            u16* __restrict__ oc) {
  const int z = blockIdx.y;
  const float* in = (z == 0) ? a : (z == 1) ? b : c;
  u16* out = (z == 0) ? oa : (z == 1) ? ob : oc;
  int i = blockIdx.x * 256 + threadIdx.x;
  float4 v = ((const float4*)in)[i];
  ushort4 o;
  o.x = f2bf(v.x); o.y = f2bf(v.y); o.z = f2bf(v.z); o.w = f2bf(v.w);
  ((ushort4*)out)[i] = o;
}

// z==0 (Wq) gets the attention scale folded in: Q' = x @ (SC*Wq)^T
__global__ __launch_bounds__(256) void cvt4(const float* __restrict__ a,
                                            const float* __restrict__ b,
                                            const float* __restrict__ c,
                                            const float* __restrict__ d,
                                            u16* __restrict__ oa, u16* __restrict__ ob,
                                            u16* __restrict__ oc, u16* __restrict__ od) {
  const int z = blockIdx.y;
  const float* in = (z == 0) ? a : (z == 1) ? b : (z == 2) ? c : d;
  u16* out = (z == 0) ? oa : (z == 1) ? ob : (z == 2) ? oc : od;
  const float s = (z == 0) ? SC : 1.0f;
  int i = blockIdx.x * 256 + threadIdx.x;
  float4 v = ((const float4*)in)[i];
  ushort4 o;
  o.x = f2bf(v.x * s); o.y = f2bf(v.y * s); o.z = f2bf(v.z * s); o.w = f2bf(v.w * s);
  ((ushort4*)out)[i] = o;
}

// ================= deep-pipelined GEMM core (C = A @ B^T) =================
// BM=256 x BN=128 x BK=64, 512 threads = 8 waves in a 4(M) x 2(N) grid;
// per-wave 64x64 output = 4x4 MFMA fragments (identical fragment/swizzle code
// to the verified 128^2 kernel). Double-buffered LDS (96 KiB), staging via
// global_load_lds issued TWO K-tiles ahead, counted s_waitcnt vmcnt(6) (never
// a full drain in the main loop), raw s_barrier (no compiler vmcnt(0) drain).
//
// Pipeline invariant (per wave, 6 DMA issues per K-tile, issue order = tile
// order): at the head of tile kt the in-flight set is {kt (6 oldest), kt+1
// (6 newest)}; vmcnt(6) retires kt. Tile kt+2 is issued only after the
// barrier that ends all reads of buffer kt&1 (its destination).
#define BM 256
#define BN 128
#define BK 64
#define NKT (D_MODEL / BK)   // 16

static __device__ __forceinline__ void gemm_core(const u16* __restrict__ A,
                                                 const u16* __restrict__ B,
                                                 u16* As, u16* Bs,
                                                 int m0, int n0, f32x4 acc[4][4]) {
  const int t = threadIdx.x;
  const int lane = t & 63, wave = t >> 6;
  const int wm = wave >> 1, wn = wave & 1;          // 4 x 2 wave grid
  const int lrow = lane & 15, quad = lane >> 4;
  const int srow = t >> 3;                          // 0..63: staged row within issue
  const int swcol = (((t & 7) ^ (srow & 7)) << 3);  // pre-swizzled global column
  const int sdst = srow * 64 + (t & 7) * 8;         // linear LDS dest (u16)
  const int rsw = lrow & 7;                         // reader-side swizzle key

#pragma unroll
  for (int i = 0; i < 4; i++)
#pragma unroll
    for (int j = 0; j < 4; j++) acc[i][j] = (f32x4){0.f, 0.f, 0.f, 0.f};

  // stage K-tile kt_ into buffer bi_: 6 global_load_lds per wave
#define STAGE_(kt_, bi_)                                                        \
  do {                                                                          \
    const int k0_ = (kt_)*BK;                                                   \
    u16* as_ = As + (bi_) * (BM * BK);                                          \
    u16* bs_ = Bs + (bi_) * (BN * BK);                                          \
    _Pragma("unroll") for (int r_ = 0; r_ < 4; ++r_)                            \
        gload_lds16(A + (size_t)(m0 + r_ * 64 + srow) * 1024 + k0_ + swcol,     \
                    as_ + r_ * 64 * 64 + sdst);                                 \
    _Pragma("unroll") for (int r_ = 0; r_ < 2; ++r_)                            \
        gload_lds16(B + (size_t)(n0 + r_ * 64 + srow) * 1024 + k0_ + swcol,     \
                    bs_ + r_ * 64 * 64 + sdst);                                 \
  } while (0)

  STAGE_(0, 0);
  STAGE_(1, 1);

  for (int kt = 0; kt < NKT; ++kt) {
    // retire tile kt (oldest 6 in flight); keep kt+1's loads in flight
    if (kt < NKT - 1) asm volatile("s_waitcnt vmcnt(6)" ::: "memory");
    else              asm volatile("s_waitcnt vmcnt(0)" ::: "memory");
    __builtin_amdgcn_s_barrier();        // all waves' kt data visible
    asm volatile("" ::: "memory");

    const u16* as = As + (kt & 1) * (BM * BK);
    const u16* bs = Bs + (kt & 1) * (BN * BK);

    // 4 sub-phases: 2x2 quadrants of the 4x4 fragment grid, 8 MFMA each
#pragma unroll
    for (int qi = 0; qi < 2; ++qi)
#pragma unroll
      for (int qj = 0; qj < 2; ++qj) {
        bf16x8 af[2][2], bfr[2][2];
#pragma unroll
        for (int ks = 0; ks < 2; ++ks) {
          const int cx = ((ks * 4 + quad) ^ rsw) << 3;
#pragma unroll
          for (int u = 0; u < 2; ++u) {
            af[u][ks] = *(const bf16x8*)(as + (wm * 64 + (qi * 2 + u) * 16 + lrow) * 64 + cx);
            bfr[u][ks] = *(const bf16x8*)(bs + (wn * 64 + (qj * 2 + u) * 16 + lrow) * 64 + cx);
          }
        }
        __builtin_amdgcn_s_setprio(1);
#pragma unroll
        for (int u = 0; u < 2; ++u)
#pragma unroll
          for (int v = 0; v < 2; ++v)
#pragma unroll
            for (int ks = 0; ks < 2; ++ks)
              acc[qi * 2 + u][qj * 2 + v] =
                  MFMA(af[u][ks], bfr[v][ks], acc[qi * 2 + u][qj * 2 + v]);
        __builtin_amdgcn_s_setprio(0);
      }

    // free buffer (kt&1) and refill it with tile kt+2
    if (kt + 2 < NKT) {
      asm volatile("" ::: "memory");
      __builtin_amdgcn_sched_barrier(0);
      __builtin_amdgcn_s_barrier();      // all waves done reading buf kt&1
      STAGE_(kt + 2, kt & 1);
    }
  }
#undef STAGE_
}

// ---- fused QKV projection: C = A @ W^T ----
// z=0 -> Q (scale pre-folded in Wqb); z=1 -> K; z=2 -> V TRANSPOSED [b][n][t]
__global__ __launch_bounds__(512, 2) void gemm_qkv(const u16* __restrict__ xq,
                                                   const u16* __restrict__ xk,
                                                   const u16* __restrict__ xv,
                                                   const u16* __restrict__ Wqb,
                                                   const u16* __restrict__ Wkb,
                                                   const u16* __restrict__ Wvb,
                                                   u16* __restrict__ Qb, u16* __restrict__ Kb,
                                                   u16* __restrict__ Vtg, int zbase) {
  __shared__ u16 As[2 * BM * BK];   // 64 KiB
  __shared__ u16 Bs[2 * BN * BK];   // 32 KiB
  const int z = blockIdx.z + zbase;
  const u16* A = (z == 0) ? xq : (z == 1) ? xk : xv;
  const u16* B = (z == 0) ? Wqb : (z == 1) ? Wkb : Wvb;
  const int m0 = blockIdx.x * BM, n0 = blockIdx.y * BN;

  f32x4 acc[4][4];
  gemm_core(A, B, As, Bs, m0, n0, acc);

  const int lane = threadIdx.x & 63, wave = threadIdx.x >> 6;
  const int wm = wave >> 1, wn = wave & 1;
  const int lrow = lane & 15, quad = lane >> 4;

  // C/D: col = lane&15 (n), row = quad*4 + reg (m)
  if (z == 2) {
    const int b = m0 >> 11;
    const int t0 = (m0 & 2047);
#pragma unroll
    for (int i = 0; i < 4; i++) {
      const int trow = t0 + wm * 64 + i * 16 + quad * 4;
#pragma unroll
      for (int j = 0; j < 4; j++) {
        const int n = n0 + wn * 64 + j * 16 + lrow;
        ushort4 pk;
        pk.x = f2bf(acc[i][j][0]); pk.y = f2bf(acc[i][j][1]);
        pk.z = f2bf(acc[i][j][2]); pk.w = f2bf(acc[i][j][3]);
        *(ushort4*)(Vtg + (size_t)b * D_MODEL * SEQ + (size_t)n * SEQ + trow) = pk;
      }
    }
  } else {
    u16* C = z ? Kb : Qb;
#pragma unroll
    for (int i = 0; i < 4; i++) {
      const int mr = m0 + wm * 64 + i * 16 + quad * 4;
#pragma unroll
      for (int j = 0; j < 4; j++) {
        const int n = n0 + wn * 64 + j * 16 + lrow;
#pragma unroll
        for (int r = 0; r < 4; r++) C[(size_t)(mr + r) * 1024 + n] = f2bf(acc[i][j][r]);
      }
    }
  }
}

// ---- output projection: f32 out ----
__global__ __launch_bounds__(512, 2) void gemm_o(const u16* __restrict__ A,
                                                 const u16* __restrict__ B,
                                                 float* __restrict__ C) {
  __shared__ u16 As[2 * BM * BK];
  __shared__ u16 Bs[2 * BN * BK];
  const int m0 = blockIdx.x * BM, n0 = blockIdx.y * BN;

  f32x4 acc[4][4];
  gemm_core(A, B, As, Bs, m0, n0, acc);

  const int lane = threadIdx.x & 63, wave = threadIdx.x >> 6;
  const int wm = wave >> 1, wn = wave & 1;
  const int lrow = lane & 15, quad = lane >> 4;
#pragma unroll
  for (int i = 0; i < 4; i++) {
    const int mr = m0 + wm * 64 + i * 16 + quad * 4;
#pragma unroll
    for (int j = 0; j < 4; j++) {
      const int n = n0 + wn * 64 + j * 16 + lrow;
#pragma unroll
      for (int r = 0; r < 4; r++) C[(size_t)(mr + r) * 1024 + n] = acc[i][j][r];
    }
  }
}

// ---- causal flash attention, v3 (unchanged this round) ----
__global__ __launch_bounds__(256) void attn_causal(const u16* __restrict__ Qb,
                                                   const u16* __restrict__ Kb,
                                                   const u16* __restrict__ Vtg,
                                                   u16* __restrict__ Ob) {
  __shared__ u16 QPs[128 * 64];  // 16 KB: Q staging, then P
  __shared__ u16 Ks[64 * 64];    // 8 KB
  __shared__ u16 Vs[64 * 64];    // 8 KB  V^T tile [d][j]

  const int t = threadIdx.x;
  const int lane = t & 63, wave = t >> 6;
  const int lrow = lane & 15, quad = lane >> 4;
  const int wb = wave * 32;
  const int bh = blockIdx.x;
  const int b = bh >> 4, h = bh & 15;
  const int col0 = h * 64;
  const size_t rowbase = (size_t)b * SEQ;
  const size_t vbase = (size_t)b * (size_t)D_MODEL * SEQ;
  const int srow = t >> 3;
  const int swcol = (((t & 7) ^ (srow & 7)) << 3);
  const int pchunk = (t & 7) * 8;
  const int rsw = lrow & 7;

  // ones B-column (n=0): lanes with lrow==0 hold 1.0 in all k slots
  bf16x8 bOnes;
  {
    const short ov = (lrow == 0) ? (short)0x3F80 : (short)0;
#pragma unroll
    for (int e = 0; e < 8; ++e) bOnes[e] = ov;
  }

  for (int part = 0; part < 2; ++part) {
    const int qt = part ? (15 - (int)blockIdx.y) : (int)blockIdx.y;
    const int qrow0 = qt * 128;

    // stage Q tile (async; drained by first k-tile's second barrier)
#pragma unroll
    for (int r = 0; r < 4; ++r) {
      int rr = r * 32 + srow;
      gload_lds16(Qb + (rowbase + qrow0 + rr) * D_MODEL + col0 + swcol,
                  QPs + rr * 64 + pchunk);
    }

    bf16x8 bQ[2][2];     // Q fragments in registers (loop-invariant)
    f32x4 oacc[2][4];    // O[m][d]: [mf][df]
    f32x4 lacc[2];       // l at col 0
#pragma unroll
    for (int mf = 0; mf < 2; mf++) {
#pragma unroll
      for (int df = 0; df < 4; df++) oacc[mf][df] = (f32x4){0.f, 0.f, 0.f, 0.f};
      lacc[mf] = (f32x4){0.f, 0.f, 0.f, 0.f};
    }

    const int nkt = 2 * qt + 2;
    for (int kt = 0; kt < nkt; ++kt) {
      const int j0 = kt * 64;
      __syncthreads();  // prev-iter Ks/Vs/Ps reads complete
#pragma unroll
      for (int r = 0; r < 2; ++r) {
        int rr = r * 32 + srow;
        gload_lds16(Kb + (rowbase + j0 + rr) * D_MODEL + col0 + swcol,
                    Ks + rr * 64 + pchunk);
        gload_lds16(Vtg + vbase + (size_t)(col0 + rr) * SEQ + j0 + swcol,
                    Vs + rr * 64 + pchunk);
      }
      __syncthreads();  // drains vmcnt (incl. Qs on kt==0)

      if (kt == 0) {
#pragma unroll
        for (int mf = 0; mf < 2; ++mf)
#pragma unroll
          for (int ks = 0; ks < 2; ++ks)
            bQ[mf][ks] = *(const bf16x8*)(QPs + (wb + mf * 16 + lrow) * 64 +
                                          (((ks * 4 + quad) ^ rsw) << 3));
      }

      const bool diag = (kt >= 2 * qt);
      // S^T = K·Q^T per mf half; softmax; P -> QPs (ushort4, swizzled)
#pragma unroll
      for (int mf = 0; mf < 2; ++mf) {
        f32x4 st[4];
#pragma unroll
        for (int jf = 0; jf < 4; jf++) st[jf] = (f32x4){0.f, 0.f, 0.f, 0.f};
#pragma unroll
        for (int ks = 0; ks < 2; ++ks) {
          const int cx = ((ks * 4 + quad) ^ rsw) << 3;
#pragma unroll
          for (int jf = 0; jf < 4; jf++) {
            bf16x8 aK = *(const bf16x8*)(Ks + (jf * 16 + lrow) * 64 + cx);
            st[jf] = MFMA(aK, bQ[mf][ks], st[jf]);
          }
        }
        // st[jf] rows: j = j0 + jf*16 + quad*4 + r ; col: m = wb + mf*16 + lrow
        const int m = wb + mf * 16 + lrow;
        const int gm = qrow0 + m;
#pragma unroll
        for (int jf = 0; jf < 4; jf++) {
          ushort4 pk;
#pragma unroll
          for (int r = 0; r < 4; r++) {
            float p = __builtin_amdgcn_exp2f(st[jf][r]);  // scale pre-folded
            const int gj = j0 + jf * 16 + quad * 4 + r;
            if (diag && gj > gm) p = 0.f;
            ((u16*)&pk)[r] = f2bf_t(p);
          }
          const int j = jf * 16 + quad * 4;
          *(ushort4*)(QPs + m * 64 + ((((j >> 3) ^ (m & 7)) << 3) | (j & 7))) = pk;
        }
      }

      // O += P·V^T ; l += P·1  (QPs rows are wave-private: no barrier)
#pragma unroll
      for (int ks = 0; ks < 2; ++ks) {
        const int cx = ((ks * 4 + quad) ^ rsw) << 3;  // (m&7)==rsw for our rows
        bf16x8 aP[2];
#pragma unroll
        for (int mf = 0; mf < 2; ++mf)
          aP[mf] = *(const bf16x8*)(QPs + (wb + mf * 16 + lrow) * 64 + cx);
        lacc[0] = MFMA(aP[0], bOnes, lacc[0]);
        lacc[1] = MFMA(aP[1], bOnes, lacc[1]);
#pragma unroll
        for (int df = 0; df < 4; df++) {
          bf16x8 bV = *(const bf16x8*)(Vs + (df * 16 + lrow) * 64 + cx);
          oacc[0][df] = MFMA(aP[0], bV, oacc[0][df]);
          oacc[1][df] = MFMA(aP[1], bV, oacc[1][df]);
        }
      }
    }
    __syncthreads();  // all waves done with QPs/Ks/Vs before next part restages

    // l[m = quad*4+r] sits in lacc[mf][r] at lane quad*16 (col 0)
    float linv[2][4];
#pragma unroll
    for (int mf = 0; mf < 2; mf++)
#pragma unroll
      for (int r = 0; r < 4; r++)
        linv[mf][r] = 1.0f / __shfl(lacc[mf][r], lane & 48);

    // store O: row = qrow0 + wb + mf*16 + quad*4 + r, col = col0 + df*16 + lrow
#pragma unroll
    for (int mf = 0; mf < 2; mf++)
#pragma unroll
      for (int r = 0; r < 4; r++) {
        u16* orow = Ob + (rowbase + qrow0 + wb + mf * 16 + quad * 4 + r) * D_MODEL + col0;
#pragma unroll
        for (int df = 0; df < 4; df++)
          orow[df * 16 + lrow] = f2bf(oacc[mf][df][r] * linv[mf][r]);
      }
  }
}

extern "C" void kernel_launch(void* const* d_in, const int* in_sizes, int n_in,
                              void* d_out, int out_size, void* d_ws, size_t ws_size,
                              hipStream_t stream) {
  const float* q  = (const float*)d_in[0];
  const float* k  = (const float*)d_in[1];
  const float* v  = (const float*)d_in[2];
  // d_in[3] = mask — strict-upper-triangle causal; handled analytically
  const float* Wq = (const float*)d_in[4];
  const float* Wk = (const float*)d_in[5];
  const float* Wv = (const float*)d_in[6];
  const float* Wo = (const float*)d_in[7];
  float* out = (float*)d_out;

  char* ws = (char*)d_ws;
  const size_t MB = 1 << 20;
  u16* xq  = (u16*)(ws);
  u16* xk  = (u16*)(ws + 16 * MB);
  u16* xv  = (u16*)(ws + 32 * MB);
  u16* Wqb = (u16*)(ws + 48 * MB);
  u16* Wkb = (u16*)(ws + 50 * MB);
  u16* Wvb = (u16*)(ws + 52 * MB);
  u16* Wob = (u16*)(ws + 54 * MB);
  u16* Qb  = (u16*)(ws + 56 * MB);

  const dim3 cb(256);
  const dim3 gb(512);
  cvt3<<<dim3(MTOT * D_MODEL / 4 / 256, 3), cb, 0, stream>>>(q, k, v, xq, xk, xv);
  cvt4<<<dim3(D_MODEL * D_MODEL / 4 / 256, 4), cb, 0, stream>>>(Wq, Wk, Wv, Wo,
                                                                Wqb, Wkb, Wvb, Wob);

  if (ws_size >= 104 * MB) {
    u16* Kb  = (u16*)(ws + 72 * MB);
    u16* Vtg = (u16*)(ws + 88 * MB);
    gemm_qkv<<<dim3(32, 8, 3), gb, 0, stream>>>(xq, xk, xv, Wqb, Wkb, Wvb,
                                                Qb, Kb, Vtg, 0);
    attn_causal<<<dim3(64, 8), cb, 0, stream>>>(Qb, Kb, Vtg, xq);  // O -> xq
    gemm_o<<<dim3(32, 8), gb, 0, stream>>>(xq, Wob, out);
  } else {
    u16* Kb  = (u16*)(ws);
    u16* Vtg = (u16*)(ws + 16 * MB);
    u16* Oatt = (u16*)(ws + 32 * MB);
    gemm_qkv<<<dim3(32, 8, 1), gb, 0, stream>>>(xq, xq, xq, Wqb, Wqb, Wqb,
                                                Qb, Qb, Qb, 0);
    gemm_qkv<<<dim3(32, 8, 1), gb, 0, stream>>>(xk, xk, xk, Wkb, Wkb, Wkb,
                                                Kb, Kb, Kb, 1);
    gemm_qkv<<<dim3(32, 8, 1), gb, 0, stream>>>(xv, xv, xv, Wvb, Wvb, Wvb,
                                                Vtg, Vtg, Vtg, 2);
    attn_causal<<<dim3(64, 8), cb, 0, stream>>>(Qb, Kb, Vtg, Oatt);
    gemm_o<<<dim3(64, 8), cb, 0, stream>>>(Oatt, Wob, out);
  }
}

// Round 2
// 320.109 us; speedup vs baseline: 1.0052x; 1.0052x over previous
//
#include <hip/hip_runtime.h>
#include <stdint.h>

#define D_MODEL 1024
#define N_HEADS 16
#define D_HEAD 64
#define BATCH 4
#define SEQ 2048
#define MTOT (BATCH * SEQ)   // 8192

typedef unsigned short u16;
typedef __attribute__((ext_vector_type(8))) short bf16x8;
typedef __attribute__((ext_vector_type(4))) float f32x4;

#define MFMA(a, b, c) __builtin_amdgcn_mfma_f32_16x16x32_bf16((a), (b), (c), 0, 0, 0)
#define LOG2E 1.4426950408889634f
#define SC (0.125f * LOG2E)   // folded into Wq at cvt time

// fp32 -> bf16 bits, round-to-nearest-even
static __device__ __forceinline__ u16 f2bf(float f) {
  unsigned u = __builtin_bit_cast(unsigned, f);
  u += 0x7fffu + ((u >> 16) & 1u);
  return (u16)(u >> 16);
}
// truncating (1 inst) — for p >= 0, error < 1 ulp
static __device__ __forceinline__ u16 f2bf_t(float f) {
  return (u16)(__builtin_bit_cast(unsigned, f) >> 16);
}

// async 16B global->LDS (dest = wave-uniform base + lane*16)
static __device__ __forceinline__ void gload_lds16(const void* g, void* l) {
  __builtin_amdgcn_global_load_lds(
      (const __attribute__((address_space(1))) void*)g,
      (__attribute__((address_space(3))) void*)l, 16, 0, 0);
}

// ---- converts ----
__global__ __launch_bounds__(256) void cvt3(const float* __restrict__ a,
                                            const float* __restrict__ b,
                                            const float* __restrict__ c,
                                            u16* __restrict__ oa, u16* __restrict__ ob,
                                            u16* __restrict__ oc) {
  const int z = blockIdx.y;
  const float* in = (z == 0) ? a : (z == 1) ? b : c;
  u16* out = (z == 0) ? oa : (z == 1) ? ob : oc;
  int i = blockIdx.x * 256 + threadIdx.x;
  float4 v = ((const float4*)in)[i];
  ushort4 o;
  o.x = f2bf(v.x); o.y = f2bf(v.y); o.z = f2bf(v.z); o.w = f2bf(v.w);
  ((ushort4*)out)[i] = o;
}

// z==0 (Wq) gets the attention scale folded in: Q' = x @ (SC*Wq)^T
__global__ __launch_bounds__(256) void cvt4(const float* __restrict__ a,
                                            const float* __restrict__ b,
                                            const float* __restrict__ c,
                                            const float* __restrict__ d,
                                            u16* __restrict__ oa, u16* __restrict__ ob,
                                            u16* __restrict__ oc, u16* __restrict__ od) {
  const int z = blockIdx.y;
  const float* in = (z == 0) ? a : (z == 1) ? b : (z == 2) ? c : d;
  u16* out = (z == 0) ? oa : (z == 1) ? ob : (z == 2) ? oc : od;
  const float s = (z == 0) ? SC : 1.0f;
  int i = blockIdx.x * 256 + threadIdx.x;
  float4 v = ((const float4*)in)[i];
  ushort4 o;
  o.x = f2bf(v.x * s); o.y = f2bf(v.y * s); o.z = f2bf(v.z * s); o.w = f2bf(v.w * s);
  ((ushort4*)out)[i] = o;
}

// ================= deep-pipelined GEMM core (C = A @ B^T) =================
// BM=256 x BN=128 x BK=64, 512 threads = 8 waves in a 4(M) x 2(N) grid;
// per-wave 64x64 output = 4x4 MFMA fragments. Double-buffered LDS (96 KiB),
// staging via global_load_lds issued TWO K-tiles ahead, counted s_waitcnt
// vmcnt(6) (never a full drain in the main loop), raw s_barrier.
//
// Inner loop is the DEDUP'd fragment pattern: per ks, read a[4]+b[4] ONCE
// (8 ds_read_b128) then 16 MFMA — 16 reads / 32 MFMA per K-tile per wave,
// the minimum LDS traffic for a 64x64 wave tile. (Round-1's quadrant split
// doubled LDS reads -> LDS-BW-bound at 25% MfmaUtil.)
//
// Pipeline invariant (per wave, 6 DMA issues per K-tile, issue order = tile
// order): at the head of tile kt the in-flight set is {kt (6 oldest), kt+1
// (6 newest)}; vmcnt(6) retires kt. Tile kt+2 is issued only after the
// barrier that ends all reads of buffer kt&1 (its destination).
#define BM 256
#define BN 128
#define BK 64
#define NKT (D_MODEL / BK)   // 16

static __device__ __forceinline__ void gemm_core(const u16* __restrict__ A,
                                                 const u16* __restrict__ B,
                                                 u16* As, u16* Bs,
                                                 int m0, int n0, f32x4 acc[4][4]) {
  const int t = threadIdx.x;
  const int lane = t & 63, wave = t >> 6;
  const int wm = wave >> 1, wn = wave & 1;          // 4 x 2 wave grid
  const int lrow = lane & 15, quad = lane >> 4;
  const int srow = t >> 3;                          // 0..63: staged row within issue
  const int swcol = (((t & 7) ^ (srow & 7)) << 3);  // pre-swizzled global column
  const int sdst = srow * 64 + (t & 7) * 8;         // linear LDS dest (u16)
  const int rsw = lrow & 7;                         // reader-side swizzle key

#pragma unroll
  for (int i = 0; i < 4; i++)
#pragma unroll
    for (int j = 0; j < 4; j++) acc[i][j] = (f32x4){0.f, 0.f, 0.f, 0.f};

  // stage K-tile kt_ into buffer bi_: 6 global_load_lds per wave
#define STAGE_(kt_, bi_)                                                        \
  do {                                                                          \
    const int k0_ = (kt_)*BK;                                                   \
    u16* as_ = As + (bi_) * (BM * BK);                                          \
    u16* bs_ = Bs + (bi_) * (BN * BK);                                          \
    _Pragma("unroll") for (int r_ = 0; r_ < 4; ++r_)                            \
        gload_lds16(A + (size_t)(m0 + r_ * 64 + srow) * 1024 + k0_ + swcol,     \
                    as_ + r_ * 64 * 64 + sdst);                                 \
    _Pragma("unroll") for (int r_ = 0; r_ < 2; ++r_)                            \
        gload_lds16(B + (size_t)(n0 + r_ * 64 + srow) * 1024 + k0_ + swcol,     \
                    bs_ + r_ * 64 * 64 + sdst);                                 \
  } while (0)

  STAGE_(0, 0);
  STAGE_(1, 1);

  for (int kt = 0; kt < NKT; ++kt) {
    // retire tile kt (oldest 6 in flight); keep kt+1's loads in flight
    if (kt < NKT - 1) asm volatile("s_waitcnt vmcnt(6)" ::: "memory");
    else              asm volatile("s_waitcnt vmcnt(0)" ::: "memory");
    __builtin_amdgcn_s_barrier();        // all waves' kt data visible
    asm volatile("" ::: "memory");

    const u16* as = As + (kt & 1) * (BM * BK);
    const u16* bs = Bs + (kt & 1) * (BN * BK);

#pragma unroll
    for (int ks = 0; ks < 2; ++ks) {
      const int cx = ((ks * 4 + quad) ^ rsw) << 3;
      bf16x8 a[4], b[4];
#pragma unroll
      for (int i = 0; i < 4; i++)
        a[i] = *(const bf16x8*)(as + (wm * 64 + i * 16 + lrow) * 64 + cx);
#pragma unroll
      for (int j = 0; j < 4; j++)
        b[j] = *(const bf16x8*)(bs + (wn * 64 + j * 16 + lrow) * 64 + cx);
      __builtin_amdgcn_s_setprio(1);
#pragma unroll
      for (int i = 0; i < 4; i++)
#pragma unroll
        for (int j = 0; j < 4; j++) acc[i][j] = MFMA(a[i], b[j], acc[i][j]);
      __builtin_amdgcn_s_setprio(0);
    }

    // free buffer (kt&1) and refill it with tile kt+2
    if (kt + 2 < NKT) {
      asm volatile("" ::: "memory");
      __builtin_amdgcn_sched_barrier(0);
      __builtin_amdgcn_s_barrier();      // all waves done reading buf kt&1
      STAGE_(kt + 2, kt & 1);
    }
  }
#undef STAGE_
}

// ---- fused QKV projection: C = A @ W^T ----
// z=0 -> Q (scale pre-folded in Wqb); z=1 -> K; z=2 -> V TRANSPOSED [b][n][t]
__global__ __launch_bounds__(512, 2) void gemm_qkv(const u16* __restrict__ xq,
                                                   const u16* __restrict__ xk,
                                                   const u16* __restrict__ xv,
                                                   const u16* __restrict__ Wqb,
                                                   const u16* __restrict__ Wkb,
                                                   const u16* __restrict__ Wvb,
                                                   u16* __restrict__ Qb, u16* __restrict__ Kb,
                                                   u16* __restrict__ Vtg, int zbase) {
  __shared__ u16 As[2 * BM * BK];   // 64 KiB
  __shared__ u16 Bs[2 * BN * BK];   // 32 KiB
  const int z = blockIdx.z + zbase;
  const u16* A = (z == 0) ? xq : (z == 1) ? xk : xv;
  const u16* B = (z == 0) ? Wqb : (z == 1) ? Wkb : Wvb;
  const int m0 = blockIdx.x * BM, n0 = blockIdx.y * BN;

  f32x4 acc[4][4];
  gemm_core(A, B, As, Bs, m0, n0, acc);

  const int lane = threadIdx.x & 63, wave = threadIdx.x >> 6;
  const int wm = wave >> 1, wn = wave & 1;
  const int lrow = lane & 15, quad = lane >> 4;

  // C/D: col = lane&15 (n), row = quad*4 + reg (m)
  if (z == 2) {
    const int b = m0 >> 11;
    const int t0 = (m0 & 2047);
#pragma unroll
    for (int i = 0; i < 4; i++) {
      const int trow = t0 + wm * 64 + i * 16 + quad * 4;
#pragma unroll
      for (int j = 0; j < 4; j++) {
        const int n = n0 + wn * 64 + j * 16 + lrow;
        ushort4 pk;
        pk.x = f2bf(acc[i][j][0]); pk.y = f2bf(acc[i][j][1]);
        pk.z = f2bf(acc[i][j][2]); pk.w = f2bf(acc[i][j][3]);
        *(ushort4*)(Vtg + (size_t)b * D_MODEL * SEQ + (size_t)n * SEQ + trow) = pk;
      }
    }
  } else {
    u16* C = z ? Kb : Qb;
#pragma unroll
    for (int i = 0; i < 4; i++) {
      const int mr = m0 + wm * 64 + i * 16 + quad * 4;
#pragma unroll
      for (int j = 0; j < 4; j++) {
        const int n = n0 + wn * 64 + j * 16 + lrow;
#pragma unroll
        for (int r = 0; r < 4; r++) C[(size_t)(mr + r) * 1024 + n] = f2bf(acc[i][j][r]);
      }
    }
  }
}

// ---- output projection: f32 out ----
__global__ __launch_bounds__(512, 2) void gemm_o(const u16* __restrict__ A,
                                                 const u16* __restrict__ B,
                                                 float* __restrict__ C) {
  __shared__ u16 As[2 * BM * BK];
  __shared__ u16 Bs[2 * BN * BK];
  const int m0 = blockIdx.x * BM, n0 = blockIdx.y * BN;

  f32x4 acc[4][4];
  gemm_core(A, B, As, Bs, m0, n0, acc);

  const int lane = threadIdx.x & 63, wave = threadIdx.x >> 6;
  const int wm = wave >> 1, wn = wave & 1;
  const int lrow = lane & 15, quad = lane >> 4;
#pragma unroll
  for (int i = 0; i < 4; i++) {
    const int mr = m0 + wm * 64 + i * 16 + quad * 4;
#pragma unroll
    for (int j = 0; j < 4; j++) {
      const int n = n0 + wn * 64 + j * 16 + lrow;
#pragma unroll
      for (int r = 0; r < 4; r++) C[(size_t)(mr + r) * 1024 + n] = acc[i][j][r];
    }
  }
}

// ---- causal flash attention, v3 (unchanged this round) ----
__global__ __launch_bounds__(256) void attn_causal(const u16* __restrict__ Qb,
                                                   const u16* __restrict__ Kb,
                                                   const u16* __restrict__ Vtg,
                                                   u16* __restrict__ Ob) {
  __shared__ u16 QPs[128 * 64];  // 16 KB: Q staging, then P
  __shared__ u16 Ks[64 * 64];    // 8 KB
  __shared__ u16 Vs[64 * 64];    // 8 KB  V^T tile [d][j]

  const int t = threadIdx.x;
  const int lane = t & 63, wave = t >> 6;
  const int lrow = lane & 15, quad = lane >> 4;
  const int wb = wave * 32;
  const int bh = blockIdx.x;
  const int b = bh >> 4, h = bh & 15;
  const int col0 = h * 64;
  const size_t rowbase = (size_t)b * SEQ;
  const size_t vbase = (size_t)b * (size_t)D_MODEL * SEQ;
  const int srow = t >> 3;
  const int swcol = (((t & 7) ^ (srow & 7)) << 3);
  const int pchunk = (t & 7) * 8;
  const int rsw = lrow & 7;

  // ones B-column (n=0): lanes with lrow==0 hold 1.0 in all k slots
  bf16x8 bOnes;
  {
    const short ov = (lrow == 0) ? (short)0x3F80 : (short)0;
#pragma unroll
    for (int e = 0; e < 8; ++e) bOnes[e] = ov;
  }

  for (int part = 0; part < 2; ++part) {
    const int qt = part ? (15 - (int)blockIdx.y) : (int)blockIdx.y;
    const int qrow0 = qt * 128;

    // stage Q tile (async; drained by first k-tile's second barrier)
#pragma unroll
    for (int r = 0; r < 4; ++r) {
      int rr = r * 32 + srow;
      gload_lds16(Qb + (rowbase + qrow0 + rr) * D_MODEL + col0 + swcol,
                  QPs + rr * 64 + pchunk);
    }

    bf16x8 bQ[2][2];     // Q fragments in registers (loop-invariant)
    f32x4 oacc[2][4];    // O[m][d]: [mf][df]
    f32x4 lacc[2];       // l at col 0
#pragma unroll
    for (int mf = 0; mf < 2; mf++) {
#pragma unroll
      for (int df = 0; df < 4; df++) oacc[mf][df] = (f32x4){0.f, 0.f, 0.f, 0.f};
      lacc[mf] = (f32x4){0.f, 0.f, 0.f, 0.f};
    }

    const int nkt = 2 * qt + 2;
    for (int kt = 0; kt < nkt; ++kt) {
      const int j0 = kt * 64;
      __syncthreads();  // prev-iter Ks/Vs/Ps reads complete
#pragma unroll
      for (int r = 0; r < 2; ++r) {
        int rr = r * 32 + srow;
        gload_lds16(Kb + (rowbase + j0 + rr) * D_MODEL + col0 + swcol,
                    Ks + rr * 64 + pchunk);
        gload_lds16(Vtg + vbase + (size_t)(col0 + rr) * SEQ + j0 + swcol,
                    Vs + rr * 64 + pchunk);
      }
      __syncthreads();  // drains vmcnt (incl. Qs on kt==0)

      if (kt == 0) {
#pragma unroll
        for (int mf = 0; mf < 2; ++mf)
#pragma unroll
          for (int ks = 0; ks < 2; ++ks)
            bQ[mf][ks] = *(const bf16x8*)(QPs + (wb + mf * 16 + lrow) * 64 +
                                          (((ks * 4 + quad) ^ rsw) << 3));
      }

      const bool diag = (kt >= 2 * qt);
      // S^T = K·Q^T per mf half; softmax; P -> QPs (ushort4, swizzled)
#pragma unroll
      for (int mf = 0; mf < 2; ++mf) {
        f32x4 st[4];
#pragma unroll
        for (int jf = 0; jf < 4; jf++) st[jf] = (f32x4){0.f, 0.f, 0.f, 0.f};
#pragma unroll
        for (int ks = 0; ks < 2; ++ks) {
          const int cx = ((ks * 4 + quad) ^ rsw) << 3;
#pragma unroll
          for (int jf = 0; jf < 4; jf++) {
            bf16x8 aK = *(const bf16x8*)(Ks + (jf * 16 + lrow) * 64 + cx);
            st[jf] = MFMA(aK, bQ[mf][ks], st[jf]);
          }
        }
        // st[jf] rows: j = j0 + jf*16 + quad*4 + r ; col: m = wb + mf*16 + lrow
        const int m = wb + mf * 16 + lrow;
        const int gm = qrow0 + m;
#pragma unroll
        for (int jf = 0; jf < 4; jf++) {
          ushort4 pk;
#pragma unroll
          for (int r = 0; r < 4; r++) {
            float p = __builtin_amdgcn_exp2f(st[jf][r]);  // scale pre-folded
            const int gj = j0 + jf * 16 + quad * 4 + r;
            if (diag && gj > gm) p = 0.f;
            ((u16*)&pk)[r] = f2bf_t(p);
          }
          const int j = jf * 16 + quad * 4;
          *(ushort4*)(QPs + m * 64 + ((((j >> 3) ^ (m & 7)) << 3) | (j & 7))) = pk;
        }
      }

      // O += P·V^T ; l += P·1  (QPs rows are wave-private: no barrier)
#pragma unroll
      for (int ks = 0; ks < 2; ++ks) {
        const int cx = ((ks * 4 + quad) ^ rsw) << 3;  // (m&7)==rsw for our rows
        bf16x8 aP[2];
#pragma unroll
        for (int mf = 0; mf < 2; ++mf)
          aP[mf] = *(const bf16x8*)(QPs + (wb + mf * 16 + lrow) * 64 + cx);
        lacc[0] = MFMA(aP[0], bOnes, lacc[0]);
        lacc[1] = MFMA(aP[1], bOnes, lacc[1]);
#pragma unroll
        for (int df = 0; df < 4; df++) {
          bf16x8 bV = *(const bf16x8*)(Vs + (df * 16 + lrow) * 64 + cx);
          oacc[0][df] = MFMA(aP[0], bV, oacc[0][df]);
          oacc[1][df] = MFMA(aP[1], bV, oacc[1][df]);
        }
      }
    }
    __syncthreads();  // all waves done with QPs/Ks/Vs before next part restages

    // l[m = quad*4+r] sits in lacc[mf][r] at lane quad*16 (col 0)
    float linv[2][4];
#pragma unroll
    for (int mf = 0; mf < 2; mf++)
#pragma unroll
      for (int r = 0; r < 4; r++)
        linv[mf][r] = 1.0f / __shfl(lacc[mf][r], lane & 48);

    // store O: row = qrow0 + wb + mf*16 + quad*4 + r, col = col0 + df*16 + lrow
#pragma unroll
    for (int mf = 0; mf < 2; mf++)
#pragma unroll
      for (int r = 0; r < 4; r++) {
        u16* orow = Ob + (rowbase + qrow0 + wb + mf * 16 + quad * 4 + r) * D_MODEL + col0;
#pragma unroll
        for (int df = 0; df < 4; df++)
          orow[df * 16 + lrow] = f2bf(oacc[mf][df][r] * linv[mf][r]);
      }
  }
}

extern "C" void kernel_launch(void* const* d_in, const int* in_sizes, int n_in,
                              void* d_out, int out_size, void* d_ws, size_t ws_size,
                              hipStream_t stream) {
  const float* q  = (const float*)d_in[0];
  const float* k  = (const float*)d_in[1];
  const float* v  = (const float*)d_in[2];
  // d_in[3] = mask — strict-upper-triangle causal; handled analytically
  const float* Wq = (const float*)d_in[4];
  const float* Wk = (const float*)d_in[5];
  const float* Wv = (const float*)d_in[6];
  const float* Wo = (const float*)d_in[7];
  float* out = (float*)d_out;

  char* ws = (char*)d_ws;
  const size_t MB = 1 << 20;
  u16* xq  = (u16*)(ws);
  u16* xk  = (u16*)(ws + 16 * MB);
  u16* xv  = (u16*)(ws + 32 * MB);
  u16* Wqb = (u16*)(ws + 48 * MB);
  u16* Wkb = (u16*)(ws + 50 * MB);
  u16* Wvb = (u16*)(ws + 52 * MB);
  u16* Wob = (u16*)(ws + 54 * MB);
  u16* Qb  = (u16*)(ws + 56 * MB);

  const dim3 cb(256);
  const dim3 gb(512);
  cvt3<<<dim3(MTOT * D_MODEL / 4 / 256, 3), cb, 0, stream>>>(q, k, v, xq, xk, xv);
  cvt4<<<dim3(D_MODEL * D_MODEL / 4 / 256, 4), cb, 0, stream>>>(Wq, Wk, Wv, Wo,
                                                                Wqb, Wkb, Wvb, Wob);

  if (ws_size >= 104 * MB) {
    u16* Kb  = (u16*)(ws + 72 * MB);
    u16* Vtg = (u16*)(ws + 88 * MB);
    gemm_qkv<<<dim3(32, 8, 3), gb, 0, stream>>>(xq, xk, xv, Wqb, Wkb, Wvb,
                                                Qb, Kb, Vtg, 0);
    attn_causal<<<dim3(64, 8), cb, 0, stream>>>(Qb, Kb, Vtg, xq);  // O -> xq
    gemm_o<<<dim3(32, 8), gb, 0, stream>>>(xq, Wob, out);
  } else {
    u16* Kb  = (u16*)(ws);
    u16* Vtg = (u16*)(ws + 16 * MB);
    u16* Oatt = (u16*)(ws + 32 * MB);
    gemm_qkv<<<dim3(32, 8, 1), gb, 0, stream>>>(xq, xq, xq, Wqb, Wqb, Wqb,
                                                Qb, Qb, Qb, 0);
    gemm_qkv<<<dim3(32, 8, 1), gb, 0, stream>>>(xk, xk, xk, Wkb, Wkb, Wkb,
                                                Kb, Kb, Kb, 1);
    gemm_qkv<<<dim3(32, 8, 1), gb, 0, stream>>>(xv, xv, xv, Wvb, Wvb, Wvb,
                                                Vtg, Vtg, Vtg, 2);
    attn_causal<<<dim3(64, 8), cb, 0, stream>>>(Qb, Kb, Vtg, Oatt);
    gemm_o<<<dim3(32, 8), gb, 0, stream>>>(Oatt, Wob, out);
  }
}

// Round 3
// 319.215 us; speedup vs baseline: 1.0080x; 1.0028x over previous
//
#include <hip/hip_runtime.h>
#include <stdint.h>

#define D_MODEL 1024
#define N_HEADS 16
#define D_HEAD 64
#define BATCH 4
#define SEQ 2048
#define MTOT (BATCH * SEQ)   // 8192

typedef unsigned short u16;
typedef __attribute__((ext_vector_type(8))) short bf16x8;
typedef __attribute__((ext_vector_type(4))) float f32x4;

#define MFMA(a, b, c) __builtin_amdgcn_mfma_f32_16x16x32_bf16((a), (b), (c), 0, 0, 0)
#define LOG2E 1.4426950408889634f
#define SC (0.125f * LOG2E)   // folded into Wq at cvt time

// fp32 -> bf16 bits, round-to-nearest-even
static __device__ __forceinline__ u16 f2bf(float f) {
  unsigned u = __builtin_bit_cast(unsigned, f);
  u += 0x7fffu + ((u >> 16) & 1u);
  return (u16)(u >> 16);
}
// truncating (1 inst) — for p >= 0, error < 1 ulp
static __device__ __forceinline__ u16 f2bf_t(float f) {
  return (u16)(__builtin_bit_cast(unsigned, f) >> 16);
}

// async 16B global->LDS (dest = wave-uniform base + lane*16)
static __device__ __forceinline__ void gload_lds16(const void* g, void* l) {
  __builtin_amdgcn_global_load_lds(
      (const __attribute__((address_space(1))) void*)g,
      (__attribute__((address_space(3))) void*)l, 16, 0, 0);
}

// ---- converts ----
__global__ __launch_bounds__(256) void cvt3(const float* __restrict__ a,
                                            const float* __restrict__ b,
                                            const float* __restrict__ c,
                                            u16* __restrict__ oa, u16* __restrict__ ob,
                                            u16* __restrict__ oc) {
  const int z = blockIdx.y;
  const float* in = (z == 0) ? a : (z == 1) ? b : c;
  u16* out = (z == 0) ? oa : (z == 1) ? ob : oc;
  int i = blockIdx.x * 256 + threadIdx.x;
  float4 v = ((const float4*)in)[i];
  ushort4 o;
  o.x = f2bf(v.x); o.y = f2bf(v.y); o.z = f2bf(v.z); o.w = f2bf(v.w);
  ((ushort4*)out)[i] = o;
}

// z==0 (Wq) gets the attention scale folded in: Q' = x @ (SC*Wq)^T
__global__ __launch_bounds__(256) void cvt4(const float* __restrict__ a,
                                            const float* __restrict__ b,
                                            const float* __restrict__ c,
                                            const float* __restrict__ d,
                                            u16* __restrict__ oa, u16* __restrict__ ob,
                                            u16* __restrict__ oc, u16* __restrict__ od) {
  const int z = blockIdx.y;
  const float* in = (z == 0) ? a : (z == 1) ? b : (z == 2) ? c : d;
  u16* out = (z == 0) ? oa : (z == 1) ? ob : (z == 2) ? oc : od;
  const float s = (z == 0) ? SC : 1.0f;
  int i = blockIdx.x * 256 + threadIdx.x;
  float4 v = ((const float4*)in)[i];
  ushort4 o;
  o.x = f2bf(v.x * s); o.y = f2bf(v.y * s); o.z = f2bf(v.z * s); o.w = f2bf(v.w * s);
  ((ushort4*)out)[i] = o;
}

// ================= deep-pipelined GEMM core (C = A @ B^T) =================
// BM=256 x BN=128 x BK=64, 512 threads = 8 waves (4M x 2N), per-wave 64x64.
// TRIPLE-buffered LDS (144 KiB): tile kt lives in buffer kt%3. STAGE(kt+2)
// overwrites buffer (kt+2)%3 = (kt-1)%3, whose ds_reads finished before each
// wave's tile-(kt-1) MFMAs issued (HW lgkmcnt), which precede the tile-kt
// barrier — so ONE barrier per tile proves the destination is free, and
// STAGE issue + ks1 ds_read completion overlap the MFMA clusters.
// Counted s_waitcnt vmcnt(6): tile kt's 6 DMA ops are the oldest in flight,
// kt+1's 6 stay in flight across the barrier. sched_barrier(0) at loop end
// pins the schedule (register-only MFMAs must not sink past s_barrier).
#define BM 256
#define BN 128
#define BK 64
#define NKT (D_MODEL / BK)   // 16
#define ASZ (BM * BK)        // u16 elements per A tile buffer
#define BSZ (BN * BK)

static __device__ __forceinline__ void gemm_core(const u16* __restrict__ A,
                                                 const u16* __restrict__ B,
                                                 u16* As, u16* Bs,
                                                 int m0, int n0, f32x4 acc[4][4]) {
  const int t = threadIdx.x;
  const int lane = t & 63, wave = t >> 6;
  const int wm = wave >> 1, wn = wave & 1;          // 4 x 2 wave grid
  const int lrow = lane & 15, quad = lane >> 4;
  const int srow = t >> 3;                          // 0..63: staged row within issue
  const int swcol = (((t & 7) ^ (srow & 7)) << 3);  // pre-swizzled global column
  const int sdst = srow * 64 + (t & 7) * 8;         // linear LDS dest (u16)
  const int rsw = lrow & 7;                         // reader-side swizzle key

#pragma unroll
  for (int i = 0; i < 4; i++)
#pragma unroll
    for (int j = 0; j < 4; j++) acc[i][j] = (f32x4){0.f, 0.f, 0.f, 0.f};

  // stage K-tile kt_ into buffer bi_: 6 global_load_lds per wave
#define STAGE_(kt_, bi_)                                                        \
  do {                                                                          \
    const int k0_ = (kt_)*BK;                                                   \
    u16* as_ = As + (bi_)*ASZ;                                                  \
    u16* bs_ = Bs + (bi_)*BSZ;                                                  \
    _Pragma("unroll") for (int r_ = 0; r_ < 4; ++r_)                            \
        gload_lds16(A + (size_t)(m0 + r_ * 64 + srow) * 1024 + k0_ + swcol,     \
                    as_ + r_ * 64 * 64 + sdst);                                 \
    _Pragma("unroll") for (int r_ = 0; r_ < 2; ++r_)                            \
        gload_lds16(B + (size_t)(n0 + r_ * 64 + srow) * 1024 + k0_ + swcol,     \
                    bs_ + r_ * 64 * 64 + sdst);                                 \
  } while (0)

  STAGE_(0, 0);
  STAGE_(1, 1);

  for (int kt = 0; kt < NKT; ++kt) {
    // retire tile kt's 6 loads (oldest); kt+1's 6 remain in flight
    if (kt < NKT - 1) asm volatile("s_waitcnt vmcnt(6)" ::: "memory");
    else              asm volatile("s_waitcnt vmcnt(0)" ::: "memory");
    __builtin_amdgcn_s_barrier();        // all waves: kt data visible; buf (kt+2)%3 free
    asm volatile("" ::: "memory");

    if (kt + 2 < NKT) STAGE_(kt + 2, (kt + 2) % 3);  // overlaps reads + MFMA below

    const u16* as = As + (kt % 3) * ASZ;
    const u16* bs = Bs + (kt % 3) * BSZ;

    // issue both ks read-clusters up front; compiler waits lgkm(8) before
    // ks0 MFMAs, so ks1 reads complete under the ks0 MFMA cluster
    bf16x8 a[2][4], b[2][4];
#pragma unroll
    for (int ks = 0; ks < 2; ++ks) {
      const int cx = ((ks * 4 + quad) ^ rsw) << 3;
#pragma unroll
      for (int i = 0; i < 4; i++)
        a[ks][i] = *(const bf16x8*)(as + (wm * 64 + i * 16 + lrow) * 64 + cx);
#pragma unroll
      for (int j = 0; j < 4; j++)
        b[ks][j] = *(const bf16x8*)(bs + (wn * 64 + j * 16 + lrow) * 64 + cx);
    }
#pragma unroll
    for (int ks = 0; ks < 2; ++ks) {
      __builtin_amdgcn_s_setprio(1);
#pragma unroll
      for (int i = 0; i < 4; i++)
#pragma unroll
        for (int j = 0; j < 4; j++) acc[i][j] = MFMA(a[ks][i], b[ks][j], acc[i][j]);
      __builtin_amdgcn_s_setprio(0);
    }
    __builtin_amdgcn_sched_barrier(0);   // pin: nothing crosses the iteration edge
  }
#undef STAGE_
}

// ---- fused QKV projection: C = A @ W^T ----
// z=0 -> Q (scale pre-folded in Wqb); z=1 -> K; z=2 -> V TRANSPOSED [b][n][t]
__global__ __launch_bounds__(512, 2) void gemm_qkv(const u16* __restrict__ xq,
                                                   const u16* __restrict__ xk,
                                                   const u16* __restrict__ xv,
                                                   const u16* __restrict__ Wqb,
                                                   const u16* __restrict__ Wkb,
                                                   const u16* __restrict__ Wvb,
                                                   u16* __restrict__ Qb, u16* __restrict__ Kb,
                                                   u16* __restrict__ Vtg, int zbase) {
  __shared__ u16 As[3 * ASZ];   // 96 KiB
  __shared__ u16 Bs[3 * BSZ];   // 48 KiB
  const int z = blockIdx.z + zbase;
  const u16* A = (z == 0) ? xq : (z == 1) ? xk : xv;
  const u16* B = (z == 0) ? Wqb : (z == 1) ? Wkb : Wvb;
  const int m0 = blockIdx.x * BM, n0 = blockIdx.y * BN;

  f32x4 acc[4][4];
  gemm_core(A, B, As, Bs, m0, n0, acc);

  const int lane = threadIdx.x & 63, wave = threadIdx.x >> 6;
  const int wm = wave >> 1, wn = wave & 1;
  const int lrow = lane & 15, quad = lane >> 4;

  // C/D: col = lane&15 (n), row = quad*4 + reg (m)
  if (z == 2) {
    const int b = m0 >> 11;
    const int t0 = (m0 & 2047);
#pragma unroll
    for (int i = 0; i < 4; i++) {
      const int trow = t0 + wm * 64 + i * 16 + quad * 4;
#pragma unroll
      for (int j = 0; j < 4; j++) {
        const int n = n0 + wn * 64 + j * 16 + lrow;
        ushort4 pk;
        pk.x = f2bf(acc[i][j][0]); pk.y = f2bf(acc[i][j][1]);
        pk.z = f2bf(acc[i][j][2]); pk.w = f2bf(acc[i][j][3]);
        *(ushort4*)(Vtg + (size_t)b * D_MODEL * SEQ + (size_t)n * SEQ + trow) = pk;
      }
    }
  } else {
    u16* C = z ? Kb : Qb;
#pragma unroll
    for (int i = 0; i < 4; i++) {
      const int mr = m0 + wm * 64 + i * 16 + quad * 4;
#pragma unroll
      for (int j = 0; j < 4; j++) {
        const int n = n0 + wn * 64 + j * 16 + lrow;
#pragma unroll
        for (int r = 0; r < 4; r++) C[(size_t)(mr + r) * 1024 + n] = f2bf(acc[i][j][r]);
      }
    }
  }
}

// ---- output projection: f32 out ----
__global__ __launch_bounds__(512, 2) void gemm_o(const u16* __restrict__ A,
                                                 const u16* __restrict__ B,
                                                 float* __restrict__ C) {
  __shared__ u16 As[3 * ASZ];
  __shared__ u16 Bs[3 * BSZ];
  const int m0 = blockIdx.x * BM, n0 = blockIdx.y * BN;

  f32x4 acc[4][4];
  gemm_core(A, B, As, Bs, m0, n0, acc);

  const int lane = threadIdx.x & 63, wave = threadIdx.x >> 6;
  const int wm = wave >> 1, wn = wave & 1;
  const int lrow = lane & 15, quad = lane >> 4;
#pragma unroll
  for (int i = 0; i < 4; i++) {
    const int mr = m0 + wm * 64 + i * 16 + quad * 4;
#pragma unroll
    for (int j = 0; j < 4; j++) {
      const int n = n0 + wn * 64 + j * 16 + lrow;
#pragma unroll
      for (int r = 0; r < 4; r++) C[(size_t)(mr + r) * 1024 + n] = acc[i][j][r];
    }
  }
}

// ---- causal flash attention, v4: triple-buffered K/V, counted vmcnt ----
// Was: __syncthreads() pair per k-tile, the second draining vmcnt(0) — full
// HBM/L2 latency exposed every 64-column step. Now: K/V tile kt in buffer
// kt%3; STAGE(kt+2) right after the single per-tile barrier (same free-buffer
// proof as gemm_core); vmcnt(4) counted (4 DMA/wave/tile), never drained
// mid-loop. Compute section and numerics unchanged.
__global__ __launch_bounds__(256) void attn_causal(const u16* __restrict__ Qb,
                                                   const u16* __restrict__ Kb,
                                                   const u16* __restrict__ Vtg,
                                                   u16* __restrict__ Ob) {
  __shared__ u16 QPs[128 * 64];   // 16 KB: Q staging, then P
  __shared__ u16 Ks[3 * 64 * 64]; // 24 KB
  __shared__ u16 Vs[3 * 64 * 64]; // 24 KB  V^T tiles [d][j]

  const int t = threadIdx.x;
  const int lane = t & 63, wave = t >> 6;
  const int lrow = lane & 15, quad = lane >> 4;
  const int wb = wave * 32;
  const int bh = blockIdx.x;
  const int b = bh >> 4, h = bh & 15;
  const int col0 = h * 64;
  const size_t rowbase = (size_t)b * SEQ;
  const size_t vbase = (size_t)b * (size_t)D_MODEL * SEQ;
  const int srow = t >> 3;
  const int swcol = (((t & 7) ^ (srow & 7)) << 3);
  const int pchunk = (t & 7) * 8;
  const int rsw = lrow & 7;

  // stage K/V tile kt_ into buffer bi_: 4 DMA ops per wave
#define KVSTAGE_(kt_, bi_)                                                      \
  do {                                                                          \
    const int j0_ = (kt_)*64;                                                   \
    u16* ks_ = Ks + (bi_)*4096;                                                 \
    u16* vs_ = Vs + (bi_)*4096;                                                 \
    _Pragma("unroll") for (int r_ = 0; r_ < 2; ++r_) {                          \
      int rr_ = r_ * 32 + srow;                                                 \
      gload_lds16(Kb + (rowbase + j0_ + rr_) * D_MODEL + col0 + swcol,          \
                  ks_ + rr_ * 64 + pchunk);                                     \
      gload_lds16(Vtg + vbase + (size_t)(col0 + rr_) * SEQ + j0_ + swcol,       \
                  vs_ + rr_ * 64 + pchunk);                                     \
    }                                                                           \
  } while (0)

  // ones B-column (n=0): lanes with lrow==0 hold 1.0 in all k slots
  bf16x8 bOnes;
  {
    const short ov = (lrow == 0) ? (short)0x3F80 : (short)0;
#pragma unroll
    for (int e = 0; e < 8; ++e) bOnes[e] = ov;
  }

  for (int part = 0; part < 2; ++part) {
    const int qt = part ? (15 - (int)blockIdx.y) : (int)blockIdx.y;
    const int qrow0 = qt * 128;
    const int nkt = 2 * qt + 2;   // >= 2

    // stage Q tile (4 DMA), then K/V tiles 0 and 1 (4 DMA each)
#pragma unroll
    for (int r = 0; r < 4; ++r) {
      int rr = r * 32 + srow;
      gload_lds16(Qb + (rowbase + qrow0 + rr) * D_MODEL + col0 + swcol,
                  QPs + rr * 64 + pchunk);
    }
    KVSTAGE_(0, 0);
    KVSTAGE_(1, 1);

    bf16x8 bQ[2][2];     // Q fragments in registers (loop-invariant)
    f32x4 oacc[2][4];    // O[m][d]: [mf][df]
    f32x4 lacc[2];       // l at col 0
#pragma unroll
    for (int mf = 0; mf < 2; mf++) {
#pragma unroll
      for (int df = 0; df < 4; df++) oacc[mf][df] = (f32x4){0.f, 0.f, 0.f, 0.f};
      lacc[mf] = (f32x4){0.f, 0.f, 0.f, 0.f};
    }

    for (int kt = 0; kt < nkt; ++kt) {
      // tile kt's 4 DMA are the oldest in flight; kt+1's 4 stay in flight.
      // (At kt==0 this also retires the Q-stage DMA, issued before tile 0.)
      if (kt < nkt - 1) asm volatile("s_waitcnt vmcnt(4)" ::: "memory");
      else              asm volatile("s_waitcnt vmcnt(0)" ::: "memory");
      __builtin_amdgcn_s_barrier();
      asm volatile("" ::: "memory");

      if (kt + 2 < nkt) KVSTAGE_(kt + 2, (kt + 2) % 3);  // overlaps compute

      const u16* ksb = Ks + (kt % 3) * 4096;
      const u16* vsb = Vs + (kt % 3) * 4096;

      if (kt == 0) {
#pragma unroll
        for (int mf = 0; mf < 2; ++mf)
#pragma unroll
          for (int ks = 0; ks < 2; ++ks)
            bQ[mf][ks] = *(const bf16x8*)(QPs + (wb + mf * 16 + lrow) * 64 +
                                          (((ks * 4 + quad) ^ rsw) << 3));
      }

      const int j0 = kt * 64;
      const bool diag = (kt >= 2 * qt);
      // S^T = K·Q^T per mf half; softmax; P -> QPs (ushort4, swizzled)
#pragma unroll
      for (int mf = 0; mf < 2; ++mf) {
        f32x4 st[4];
#pragma unroll
        for (int jf = 0; jf < 4; jf++) st[jf] = (f32x4){0.f, 0.f, 0.f, 0.f};
#pragma unroll
        for (int ks = 0; ks < 2; ++ks) {
          const int cx = ((ks * 4 + quad) ^ rsw) << 3;
#pragma unroll
          for (int jf = 0; jf < 4; jf++) {
            bf16x8 aK = *(const bf16x8*)(ksb + (jf * 16 + lrow) * 64 + cx);
            st[jf] = MFMA(aK, bQ[mf][ks], st[jf]);
          }
        }
        // st[jf] rows: j = j0 + jf*16 + quad*4 + r ; col: m = wb + mf*16 + lrow
        const int m = wb + mf * 16 + lrow;
        const int gm = qrow0 + m;
#pragma unroll
        for (int jf = 0; jf < 4; jf++) {
          ushort4 pk;
#pragma unroll
          for (int r = 0; r < 4; r++) {
            float p = __builtin_amdgcn_exp2f(st[jf][r]);  // scale pre-folded
            const int gj = j0 + jf * 16 + quad * 4 + r;
            if (diag && gj > gm) p = 0.f;
            ((u16*)&pk)[r] = f2bf_t(p);
          }
          const int j = jf * 16 + quad * 4;
          *(ushort4*)(QPs + m * 64 + ((((j >> 3) ^ (m & 7)) << 3) | (j & 7))) = pk;
        }
      }

      // O += P·V^T ; l += P·1  (QPs rows are wave-private: no barrier)
#pragma unroll
      for (int ks = 0; ks < 2; ++ks) {
        const int cx = ((ks * 4 + quad) ^ rsw) << 3;  // (m&7)==rsw for our rows
        bf16x8 aP[2];
#pragma unroll
        for (int mf = 0; mf < 2; ++mf)
          aP[mf] = *(const bf16x8*)(QPs + (wb + mf * 16 + lrow) * 64 + cx);
        lacc[0] = MFMA(aP[0], bOnes, lacc[0]);
        lacc[1] = MFMA(aP[1], bOnes, lacc[1]);
#pragma unroll
        for (int df = 0; df < 4; df++) {
          bf16x8 bV = *(const bf16x8*)(vsb + (df * 16 + lrow) * 64 + cx);
          oacc[0][df] = MFMA(aP[0], bV, oacc[0][df]);
          oacc[1][df] = MFMA(aP[1], bV, oacc[1][df]);
        }
      }
      __builtin_amdgcn_sched_barrier(0);  // pin iteration edge (buffer-free proof)
    }
    __syncthreads();  // all waves done with QPs/Ks/Vs before next part restages

    // l[m = quad*4+r] sits in lacc[mf][r] at lane quad*16 (col 0)
    float linv[2][4];
#pragma unroll
    for (int mf = 0; mf < 2; mf++)
#pragma unroll
      for (int r = 0; r < 4; r++)
        linv[mf][r] = 1.0f / __shfl(lacc[mf][r], lane & 48);

    // store O: row = qrow0 + wb + mf*16 + quad*4 + r, col = col0 + df*16 + lrow
#pragma unroll
    for (int mf = 0; mf < 2; mf++)
#pragma unroll
      for (int r = 0; r < 4; r++) {
        u16* orow = Ob + (rowbase + qrow0 + wb + mf * 16 + quad * 4 + r) * D_MODEL + col0;
#pragma unroll
        for (int df = 0; df < 4; df++)
          orow[df * 16 + lrow] = f2bf(oacc[mf][df][r] * linv[mf][r]);
      }
  }
#undef KVSTAGE_
}

extern "C" void kernel_launch(void* const* d_in, const int* in_sizes, int n_in,
                              void* d_out, int out_size, void* d_ws, size_t ws_size,
                              hipStream_t stream) {
  const float* q  = (const float*)d_in[0];
  const float* k  = (const float*)d_in[1];
  const float* v  = (const float*)d_in[2];
  // d_in[3] = mask — strict-upper-triangle causal; handled analytically
  const float* Wq = (const float*)d_in[4];
  const float* Wk = (const float*)d_in[5];
  const float* Wv = (const float*)d_in[6];
  const float* Wo = (const float*)d_in[7];
  float* out = (float*)d_out;

  char* ws = (char*)d_ws;
  const size_t MB = 1 << 20;
  u16* xq  = (u16*)(ws);
  u16* xk  = (u16*)(ws + 16 * MB);
  u16* xv  = (u16*)(ws + 32 * MB);
  u16* Wqb = (u16*)(ws + 48 * MB);
  u16* Wkb = (u16*)(ws + 50 * MB);
  u16* Wvb = (u16*)(ws + 52 * MB);
  u16* Wob = (u16*)(ws + 54 * MB);
  u16* Qb  = (u16*)(ws + 56 * MB);

  const dim3 cb(256);
  const dim3 gb(512);
  cvt3<<<dim3(MTOT * D_MODEL / 4 / 256, 3), cb, 0, stream>>>(q, k, v, xq, xk, xv);
  cvt4<<<dim3(D_MODEL * D_MODEL / 4 / 256, 4), cb, 0, stream>>>(Wq, Wk, Wv, Wo,
                                                                Wqb, Wkb, Wvb, Wob);

  if (ws_size >= 104 * MB) {
    u16* Kb  = (u16*)(ws + 72 * MB);
    u16* Vtg = (u16*)(ws + 88 * MB);
    gemm_qkv<<<dim3(32, 8, 3), gb, 0, stream>>>(xq, xk, xv, Wqb, Wkb, Wvb,
                                                Qb, Kb, Vtg, 0);
    attn_causal<<<dim3(64, 8), cb, 0, stream>>>(Qb, Kb, Vtg, xq);  // O -> xq
    gemm_o<<<dim3(32, 8), gb, 0, stream>>>(xq, Wob, out);
  } else {
    u16* Kb  = (u16*)(ws);
    u16* Vtg = (u16*)(ws + 16 * MB);
    u16* Oatt = (u16*)(ws + 32 * MB);
    gemm_qkv<<<dim3(32, 8, 1), gb, 0, stream>>>(xq, xq, xq, Wqb, Wqb, Wqb,
                                                Qb, Qb, Qb, 0);
    gemm_qkv<<<dim3(32, 8, 1), gb, 0, stream>>>(xk, xk, xk, Wkb, Wkb, Wkb,
                                                Kb, Kb, Kb, 1);
    gemm_qkv<<<dim3(32, 8, 1), gb, 0, stream>>>(xv, xv, xv, Wvb, Wvb, Wvb,
                                                Vtg, Vtg, Vtg, 2);
    attn_causal<<<dim3(64, 8), cb, 0, stream>>>(Qb, Kb, Vtg, Oatt);
    gemm_o<<<dim3(32, 8), gb, 0, stream>>>(Oatt, Wob, out);
  }
}

// Round 4
// 317.474 us; speedup vs baseline: 1.0135x; 1.0055x over previous
//
#include <hip/hip_runtime.h>
#include <stdint.h>

#define D_MODEL 1024
#define N_HEADS 16
#define D_HEAD 64
#define BATCH 4
#define SEQ 2048
#define MTOT (BATCH * SEQ)   // 8192

typedef unsigned short u16;
typedef __attribute__((ext_vector_type(8))) short bf16x8;
typedef __attribute__((ext_vector_type(4))) float f32x4;

#define MFMA(a, b, c) __builtin_amdgcn_mfma_f32_16x16x32_bf16((a), (b), (c), 0, 0, 0)
#define LOG2E 1.4426950408889634f
#define SC (0.125f * LOG2E)   // folded into Wq at cvt time

// fp32 -> bf16 bits, round-to-nearest-even
static __device__ __forceinline__ u16 f2bf(float f) {
  unsigned u = __builtin_bit_cast(unsigned, f);
  u += 0x7fffu + ((u >> 16) & 1u);
  return (u16)(u >> 16);
}
// truncating (1 inst) — for p >= 0, error < 1 ulp
static __device__ __forceinline__ u16 f2bf_t(float f) {
  return (u16)(__builtin_bit_cast(unsigned, f) >> 16);
}

// async 16B global->LDS (dest = wave-uniform base + lane*16)
static __device__ __forceinline__ void gload_lds16(const void* g, void* l) {
  __builtin_amdgcn_global_load_lds(
      (const __attribute__((address_space(1))) void*)g,
      (__attribute__((address_space(3))) void*)l, 16, 0, 0);
}

// ---- converts ----
__global__ __launch_bounds__(256) void cvt3(const float* __restrict__ a,
                                            const float* __restrict__ b,
                                            const float* __restrict__ c,
                                            u16* __restrict__ oa, u16* __restrict__ ob,
                                            u16* __restrict__ oc) {
  const int z = blockIdx.y;
  const float* in = (z == 0) ? a : (z == 1) ? b : c;
  u16* out = (z == 0) ? oa : (z == 1) ? ob : oc;
  int i = blockIdx.x * 256 + threadIdx.x;
  float4 v = ((const float4*)in)[i];
  ushort4 o;
  o.x = f2bf(v.x); o.y = f2bf(v.y); o.z = f2bf(v.z); o.w = f2bf(v.w);
  ((ushort4*)out)[i] = o;
}

// z==0 (Wq) gets the attention scale folded in: Q' = x @ (SC*Wq)^T
__global__ __launch_bounds__(256) void cvt4(const float* __restrict__ a,
                                            const float* __restrict__ b,
                                            const float* __restrict__ c,
                                            const float* __restrict__ d,
                                            u16* __restrict__ oa, u16* __restrict__ ob,
                                            u16* __restrict__ oc, u16* __restrict__ od) {
  const int z = blockIdx.y;
  const float* in = (z == 0) ? a : (z == 1) ? b : (z == 2) ? c : d;
  u16* out = (z == 0) ? oa : (z == 1) ? ob : (z == 2) ? oc : od;
  const float s = (z == 0) ? SC : 1.0f;
  int i = blockIdx.x * 256 + threadIdx.x;
  float4 v = ((const float4*)in)[i];
  ushort4 o;
  o.x = f2bf(v.x * s); o.y = f2bf(v.y * s); o.z = f2bf(v.z * s); o.w = f2bf(v.w * s);
  ((ushort4*)out)[i] = o;
}

// ================= deep-pipelined GEMM core (C = A @ B^T) =================
// BM=256 x BN=128 x BK=64, 512 threads = 8 waves (4M x 2N), per-wave 64x64.
// TRIPLE-buffered LDS (144 KiB): tile kt lives in buffer kt%3; STAGE(kt+2)
// overwrites buffer (kt-1)%3 whose reads provably completed before the
// tile-kt barrier. Counted s_waitcnt vmcnt(6) — never drained mid-loop.
//
// NEW (R4): the intra-tile schedule is PINNED. R0-R3 all measured flat
// ~26% MfmaUtil with VGPR_Count=88 — proof the compiler re-interleaved the
// 16 ds_reads into the MFMA stream (minimizing liveness), exposing an
// lgkmcnt wait every few MFMAs with only 2 waves/SIMD to cover it. Now:
//   barrier -> STAGE issue -> ALL 16 ds_read_b128 (ks0 cluster, ks1 cluster)
//   -> sched_barrier(0) -> 32 contiguous MFMAs -> sched_barrier(0)
// so the compiler must keep all fragments live (expect VGPR ~170) and emit
// one lgkmcnt(8) before the ks0 MFMAs; ks1's reads complete under ks0's
// MFMA cluster.
#define BM 256
#define BN 128
#define BK 64
#define NKT (D_MODEL / BK)   // 16
#define ASZ (BM * BK)        // u16 elements per A tile buffer
#define BSZ (BN * BK)

static __device__ __forceinline__ void gemm_core(const u16* __restrict__ A,
                                                 const u16* __restrict__ B,
                                                 u16* As, u16* Bs,
                                                 int m0, int n0, f32x4 acc[4][4]) {
  const int t = threadIdx.x;
  const int lane = t & 63, wave = t >> 6;
  const int wm = wave >> 1, wn = wave & 1;          // 4 x 2 wave grid
  const int lrow = lane & 15, quad = lane >> 4;
  const int srow = t >> 3;                          // 0..63: staged row within issue
  const int swcol = (((t & 7) ^ (srow & 7)) << 3);  // pre-swizzled global column
  const int sdst = srow * 64 + (t & 7) * 8;         // linear LDS dest (u16)
  const int rsw = lrow & 7;                         // reader-side swizzle key

#pragma unroll
  for (int i = 0; i < 4; i++)
#pragma unroll
    for (int j = 0; j < 4; j++) acc[i][j] = (f32x4){0.f, 0.f, 0.f, 0.f};

  // stage K-tile kt_ into buffer bi_: 6 global_load_lds per wave
#define STAGE_(kt_, bi_)                                                        \
  do {                                                                          \
    const int k0_ = (kt_)*BK;                                                   \
    u16* as_ = As + (bi_)*ASZ;                                                  \
    u16* bs_ = Bs + (bi_)*BSZ;                                                  \
    _Pragma("unroll") for (int r_ = 0; r_ < 4; ++r_)                            \
        gload_lds16(A + (size_t)(m0 + r_ * 64 + srow) * 1024 + k0_ + swcol,     \
                    as_ + r_ * 64 * 64 + sdst);                                 \
    _Pragma("unroll") for (int r_ = 0; r_ < 2; ++r_)                            \
        gload_lds16(B + (size_t)(n0 + r_ * 64 + srow) * 1024 + k0_ + swcol,     \
                    bs_ + r_ * 64 * 64 + sdst);                                 \
  } while (0)

  STAGE_(0, 0);
  STAGE_(1, 1);

  for (int kt = 0; kt < NKT; ++kt) {
    // retire tile kt's 6 loads (oldest); kt+1's 6 remain in flight
    if (kt < NKT - 1) asm volatile("s_waitcnt vmcnt(6)" ::: "memory");
    else              asm volatile("s_waitcnt vmcnt(0)" ::: "memory");
    __builtin_amdgcn_s_barrier();        // all waves: kt data visible; buf (kt+2)%3 free
    asm volatile("" ::: "memory");

    if (kt + 2 < NKT) STAGE_(kt + 2, (kt + 2) % 3);  // DMA issue first (vmcnt only)

    const u16* as = As + (kt % 3) * ASZ;
    const u16* bs = Bs + (kt % 3) * BSZ;

    // ---- read phase: ALL 16 ds_read_b128, ks0 cluster then ks1 cluster ----
    bf16x8 a[2][4], b[2][4];
#pragma unroll
    for (int ks = 0; ks < 2; ++ks) {
      const int cx = ((ks * 4 + quad) ^ rsw) << 3;
#pragma unroll
      for (int i = 0; i < 4; i++)
        a[ks][i] = *(const bf16x8*)(as + (wm * 64 + i * 16 + lrow) * 64 + cx);
#pragma unroll
      for (int j = 0; j < 4; j++)
        b[ks][j] = *(const bf16x8*)(bs + (wn * 64 + j * 16 + lrow) * 64 + cx);
    }
    __builtin_amdgcn_sched_barrier(0);   // PIN: no read sinks into the MFMA phase

    // ---- MFMA phase: 32 contiguous; compiler waits lgkmcnt(8) for ks0,
    //      ks1 reads complete under the ks0 cluster ----
    __builtin_amdgcn_s_setprio(1);
#pragma unroll
    for (int ks = 0; ks < 2; ++ks)
#pragma unroll
      for (int i = 0; i < 4; i++)
#pragma unroll
        for (int j = 0; j < 4; j++) acc[i][j] = MFMA(a[ks][i], b[ks][j], acc[i][j]);
    __builtin_amdgcn_s_setprio(0);
    __builtin_amdgcn_sched_barrier(0);   // pin: nothing crosses the iteration edge
  }
#undef STAGE_
}

// ---- fused QKV projection: C = A @ W^T ----
// z=0 -> Q (scale pre-folded in Wqb); z=1 -> K; z=2 -> V TRANSPOSED [b][n][t]
__global__ __launch_bounds__(512, 2) void gemm_qkv(const u16* __restrict__ xq,
                                                   const u16* __restrict__ xk,
                                                   const u16* __restrict__ xv,
                                                   const u16* __restrict__ Wqb,
                                                   const u16* __restrict__ Wkb,
                                                   const u16* __restrict__ Wvb,
                                                   u16* __restrict__ Qb, u16* __restrict__ Kb,
                                                   u16* __restrict__ Vtg, int zbase) {
  __shared__ u16 As[3 * ASZ];   // 96 KiB
  __shared__ u16 Bs[3 * BSZ];   // 48 KiB
  const int z = blockIdx.z + zbase;
  const u16* A = (z == 0) ? xq : (z == 1) ? xk : xv;
  const u16* B = (z == 0) ? Wqb : (z == 1) ? Wkb : Wvb;
  const int m0 = blockIdx.x * BM, n0 = blockIdx.y * BN;

  f32x4 acc[4][4];
  gemm_core(A, B, As, Bs, m0, n0, acc);

  const int lane = threadIdx.x & 63, wave = threadIdx.x >> 6;
  const int wm = wave >> 1, wn = wave & 1;
  const int lrow = lane & 15, quad = lane >> 4;

  // C/D: col = lane&15 (n), row = quad*4 + reg (m)
  if (z == 2) {
    const int b = m0 >> 11;
    const int t0 = (m0 & 2047);
#pragma unroll
    for (int i = 0; i < 4; i++) {
      const int trow = t0 + wm * 64 + i * 16 + quad * 4;
#pragma unroll
      for (int j = 0; j < 4; j++) {
        const int n = n0 + wn * 64 + j * 16 + lrow;
        ushort4 pk;
        pk.x = f2bf(acc[i][j][0]); pk.y = f2bf(acc[i][j][1]);
        pk.z = f2bf(acc[i][j][2]); pk.w = f2bf(acc[i][j][3]);
        *(ushort4*)(Vtg + (size_t)b * D_MODEL * SEQ + (size_t)n * SEQ + trow) = pk;
      }
    }
  } else {
    u16* C = z ? Kb : Qb;
#pragma unroll
    for (int i = 0; i < 4; i++) {
      const int mr = m0 + wm * 64 + i * 16 + quad * 4;
#pragma unroll
      for (int j = 0; j < 4; j++) {
        const int n = n0 + wn * 64 + j * 16 + lrow;
#pragma unroll
        for (int r = 0; r < 4; r++) C[(size_t)(mr + r) * 1024 + n] = f2bf(acc[i][j][r]);
      }
    }
  }
}

// ---- output projection: f32 out ----
__global__ __launch_bounds__(512, 2) void gemm_o(const u16* __restrict__ A,
                                                 const u16* __restrict__ B,
                                                 float* __restrict__ C) {
  __shared__ u16 As[3 * ASZ];
  __shared__ u16 Bs[3 * BSZ];
  const int m0 = blockIdx.x * BM, n0 = blockIdx.y * BN;

  f32x4 acc[4][4];
  gemm_core(A, B, As, Bs, m0, n0, acc);

  const int lane = threadIdx.x & 63, wave = threadIdx.x >> 6;
  const int wm = wave >> 1, wn = wave & 1;
  const int lrow = lane & 15, quad = lane >> 4;
#pragma unroll
  for (int i = 0; i < 4; i++) {
    const int mr = m0 + wm * 64 + i * 16 + quad * 4;
#pragma unroll
    for (int j = 0; j < 4; j++) {
      const int n = n0 + wn * 64 + j * 16 + lrow;
#pragma unroll
      for (int r = 0; r < 4; r++) C[(size_t)(mr + r) * 1024 + n] = acc[i][j][r];
    }
  }
}

// ---- causal flash attention, v4: triple-buffered K/V, counted vmcnt ----
// (unchanged this round)
__global__ __launch_bounds__(256) void attn_causal(const u16* __restrict__ Qb,
                                                   const u16* __restrict__ Kb,
                                                   const u16* __restrict__ Vtg,
                                                   u16* __restrict__ Ob) {
  __shared__ u16 QPs[128 * 64];   // 16 KB: Q staging, then P
  __shared__ u16 Ks[3 * 64 * 64]; // 24 KB
  __shared__ u16 Vs[3 * 64 * 64]; // 24 KB  V^T tiles [d][j]

  const int t = threadIdx.x;
  const int lane = t & 63, wave = t >> 6;
  const int lrow = lane & 15, quad = lane >> 4;
  const int wb = wave * 32;
  const int bh = blockIdx.x;
  const int b = bh >> 4, h = bh & 15;
  const int col0 = h * 64;
  const size_t rowbase = (size_t)b * SEQ;
  const size_t vbase = (size_t)b * (size_t)D_MODEL * SEQ;
  const int srow = t >> 3;
  const int swcol = (((t & 7) ^ (srow & 7)) << 3);
  const int pchunk = (t & 7) * 8;
  const int rsw = lrow & 7;

  // stage K/V tile kt_ into buffer bi_: 4 DMA ops per wave
#define KVSTAGE_(kt_, bi_)                                                      \
  do {                                                                          \
    const int j0_ = (kt_)*64;                                                   \
    u16* ks_ = Ks + (bi_)*4096;                                                 \
    u16* vs_ = Vs + (bi_)*4096;                                                 \
    _Pragma("unroll") for (int r_ = 0; r_ < 2; ++r_) {                          \
      int rr_ = r_ * 32 + srow;                                                 \
      gload_lds16(Kb + (rowbase + j0_ + rr_) * D_MODEL + col0 + swcol,          \
                  ks_ + rr_ * 64 + pchunk);                                     \
      gload_lds16(Vtg + vbase + (size_t)(col0 + rr_) * SEQ + j0_ + swcol,       \
                  vs_ + rr_ * 64 + pchunk);                                     \
    }                                                                           \
  } while (0)

  // ones B-column (n=0): lanes with lrow==0 hold 1.0 in all k slots
  bf16x8 bOnes;
  {
    const short ov = (lrow == 0) ? (short)0x3F80 : (short)0;
#pragma unroll
    for (int e = 0; e < 8; ++e) bOnes[e] = ov;
  }

  for (int part = 0; part < 2; ++part) {
    const int qt = part ? (15 - (int)blockIdx.y) : (int)blockIdx.y;
    const int qrow0 = qt * 128;
    const int nkt = 2 * qt + 2;   // >= 2

    // stage Q tile (4 DMA), then K/V tiles 0 and 1 (4 DMA each)
#pragma unroll
    for (int r = 0; r < 4; ++r) {
      int rr = r * 32 + srow;
      gload_lds16(Qb + (rowbase + qrow0 + rr) * D_MODEL + col0 + swcol,
                  QPs + rr * 64 + pchunk);
    }
    KVSTAGE_(0, 0);
    KVSTAGE_(1, 1);

    bf16x8 bQ[2][2];     // Q fragments in registers (loop-invariant)
    f32x4 oacc[2][4];    // O[m][d]: [mf][df]
    f32x4 lacc[2];       // l at col 0
#pragma unroll
    for (int mf = 0; mf < 2; mf++) {
#pragma unroll
      for (int df = 0; df < 4; df++) oacc[mf][df] = (f32x4){0.f, 0.f, 0.f, 0.f};
      lacc[mf] = (f32x4){0.f, 0.f, 0.f, 0.f};
    }

    for (int kt = 0; kt < nkt; ++kt) {
      // tile kt's 4 DMA are the oldest in flight; kt+1's 4 stay in flight.
      // (At kt==0 this also retires the Q-stage DMA, issued before tile 0.)
      if (kt < nkt - 1) asm volatile("s_waitcnt vmcnt(4)" ::: "memory");
      else              asm volatile("s_waitcnt vmcnt(0)" ::: "memory");
      __builtin_amdgcn_s_barrier();
      asm volatile("" ::: "memory");

      if (kt + 2 < nkt) KVSTAGE_(kt + 2, (kt + 2) % 3);  // overlaps compute

      const u16* ksb = Ks + (kt % 3) * 4096;
      const u16* vsb = Vs + (kt % 3) * 4096;

      if (kt == 0) {
#pragma unroll
        for (int mf = 0; mf < 2; ++mf)
#pragma unroll
          for (int ks = 0; ks < 2; ++ks)
            bQ[mf][ks] = *(const bf16x8*)(QPs + (wb + mf * 16 + lrow) * 64 +
                                          (((ks * 4 + quad) ^ rsw) << 3));
      }

      const int j0 = kt * 64;
      const bool diag = (kt >= 2 * qt);
      // S^T = K·Q^T per mf half; softmax; P -> QPs (ushort4, swizzled)
#pragma unroll
      for (int mf = 0; mf < 2; ++mf) {
        f32x4 st[4];
#pragma unroll
        for (int jf = 0; jf < 4; jf++) st[jf] = (f32x4){0.f, 0.f, 0.f, 0.f};
#pragma unroll
        for (int ks = 0; ks < 2; ++ks) {
          const int cx = ((ks * 4 + quad) ^ rsw) << 3;
#pragma unroll
          for (int jf = 0; jf < 4; jf++) {
            bf16x8 aK = *(const bf16x8*)(ksb + (jf * 16 + lrow) * 64 + cx);
            st[jf] = MFMA(aK, bQ[mf][ks], st[jf]);
          }
        }
        // st[jf] rows: j = j0 + jf*16 + quad*4 + r ; col: m = wb + mf*16 + lrow
        const int m = wb + mf * 16 + lrow;
        const int gm = qrow0 + m;
#pragma unroll
        for (int jf = 0; jf < 4; jf++) {
          ushort4 pk;
#pragma unroll
          for (int r = 0; r < 4; r++) {
            float p = __builtin_amdgcn_exp2f(st[jf][r]);  // scale pre-folded
            const int gj = j0 + jf * 16 + quad * 4 + r;
            if (diag && gj > gm) p = 0.f;
            ((u16*)&pk)[r] = f2bf_t(p);
          }
          const int j = jf * 16 + quad * 4;
          *(ushort4*)(QPs + m * 64 + ((((j >> 3) ^ (m & 7)) << 3) | (j & 7))) = pk;
        }
      }

      // O += P·V^T ; l += P·1  (QPs rows are wave-private: no barrier)
#pragma unroll
      for (int ks = 0; ks < 2; ++ks) {
        const int cx = ((ks * 4 + quad) ^ rsw) << 3;  // (m&7)==rsw for our rows
        bf16x8 aP[2];
#pragma unroll
        for (int mf = 0; mf < 2; ++mf)
          aP[mf] = *(const bf16x8*)(QPs + (wb + mf * 16 + lrow) * 64 + cx);
        lacc[0] = MFMA(aP[0], bOnes, lacc[0]);
        lacc[1] = MFMA(aP[1], bOnes, lacc[1]);
#pragma unroll
        for (int df = 0; df < 4; df++) {
          bf16x8 bV = *(const bf16x8*)(vsb + (df * 16 + lrow) * 64 + cx);
          oacc[0][df] = MFMA(aP[0], bV, oacc[0][df]);
          oacc[1][df] = MFMA(aP[1], bV, oacc[1][df]);
        }
      }
      __builtin_amdgcn_sched_barrier(0);  // pin iteration edge (buffer-free proof)
    }
    __syncthreads();  // all waves done with QPs/Ks/Vs before next part restages

    // l[m = quad*4+r] sits in lacc[mf][r] at lane quad*16 (col 0)
    float linv[2][4];
#pragma unroll
    for (int mf = 0; mf < 2; mf++)
#pragma unroll
      for (int r = 0; r < 4; r++)
        linv[mf][r] = 1.0f / __shfl(lacc[mf][r], lane & 48);

    // store O: row = qrow0 + wb + mf*16 + quad*4 + r, col = col0 + df*16 + lrow
#pragma unroll
    for (int mf = 0; mf < 2; mf++)
#pragma unroll
      for (int r = 0; r < 4; r++) {
        u16* orow = Ob + (rowbase + qrow0 + wb + mf * 16 + quad * 4 + r) * D_MODEL + col0;
#pragma unroll
        for (int df = 0; df < 4; df++)
          orow[df * 16 + lrow] = f2bf(oacc[mf][df][r] * linv[mf][r]);
      }
  }
#undef KVSTAGE_
}

extern "C" void kernel_launch(void* const* d_in, const int* in_sizes, int n_in,
                              void* d_out, int out_size, void* d_ws, size_t ws_size,
                              hipStream_t stream) {
  const float* q  = (const float*)d_in[0];
  const float* k  = (const float*)d_in[1];
  const float* v  = (const float*)d_in[2];
  // d_in[3] = mask — strict-upper-triangle causal; handled analytically
  const float* Wq = (const float*)d_in[4];
  const float* Wk = (const float*)d_in[5];
  const float* Wv = (const float*)d_in[6];
  const float* Wo = (const float*)d_in[7];
  float* out = (float*)d_out;

  char* ws = (char*)d_ws;
  const size_t MB = 1 << 20;
  u16* xq  = (u16*)(ws);
  u16* xk  = (u16*)(ws + 16 * MB);
  u16* xv  = (u16*)(ws + 32 * MB);
  u16* Wqb = (u16*)(ws + 48 * MB);
  u16* Wkb = (u16*)(ws + 50 * MB);
  u16* Wvb = (u16*)(ws + 52 * MB);
  u16* Wob = (u16*)(ws + 54 * MB);
  u16* Qb  = (u16*)(ws + 56 * MB);

  const dim3 cb(256);
  const dim3 gb(512);
  cvt3<<<dim3(MTOT * D_MODEL / 4 / 256, 3), cb, 0, stream>>>(q, k, v, xq, xk, xv);
  cvt4<<<dim3(D_MODEL * D_MODEL / 4 / 256, 4), cb, 0, stream>>>(Wq, Wk, Wv, Wo,
                                                                Wqb, Wkb, Wvb, Wob);

  if (ws_size >= 104 * MB) {
    u16* Kb  = (u16*)(ws + 72 * MB);
    u16* Vtg = (u16*)(ws + 88 * MB);
    gemm_qkv<<<dim3(32, 8, 3), gb, 0, stream>>>(xq, xk, xv, Wqb, Wkb, Wvb,
                                                Qb, Kb, Vtg, 0);
    attn_causal<<<dim3(64, 8), cb, 0, stream>>>(Qb, Kb, Vtg, xq);  // O -> xq
    gemm_o<<<dim3(32, 8), gb, 0, stream>>>(xq, Wob, out);
  } else {
    u16* Kb  = (u16*)(ws);
    u16* Vtg = (u16*)(ws + 16 * MB);
    u16* Oatt = (u16*)(ws + 32 * MB);
    gemm_qkv<<<dim3(32, 8, 1), gb, 0, stream>>>(xq, xq, xq, Wqb, Wqb, Wqb,
                                                Qb, Qb, Qb, 0);
    gemm_qkv<<<dim3(32, 8, 1), gb, 0, stream>>>(xk, xk, xk, Wkb, Wkb, Wkb,
                                                Kb, Kb, Kb, 1);
    gemm_qkv<<<dim3(32, 8, 1), gb, 0, stream>>>(xv, xv, xv, Wvb, Wvb, Wvb,
                                                Vtg, Vtg, Vtg, 2);
    attn_causal<<<dim3(64, 8), cb, 0, stream>>>(Qb, Kb, Vtg, Oatt);
    gemm_o<<<dim3(32, 8), gb, 0, stream>>>(Oatt, Wob, out);
  }
}